// Round 7
// baseline (49.024 us; speedup 1.0000x reference)
//
#include <hip/hip_runtime.h>

#define NQ   10
#define NL   4
#define NCL  10
#define PI_F 3.14159265358979f

// DIAGNOSTIC BUILD: executes the circuit REPS times per wave so the dispatch
// outlives the harness's 39-us poison fills and appears in the rocprof top-5.
#define REPS 2

// Broadcast lane l's value to all lanes via v_readlane.
__device__ __forceinline__ float bcastf(float v, int l) {
    return __int_as_float(__builtin_amdgcn_readlane(__float_as_int(v), l));
}

// Cross-lane xor-butterfly fetch. VALU (DPP/permlane) where possible,
// imm-pattern ds_swizzle for m=4.
template<int M>
__device__ __forceinline__ float xlane(float v) {
    if constexpr (M == 1) {        // quad_perm [1,0,3,2]
        return __int_as_float(__builtin_amdgcn_update_dpp(
            __float_as_int(v), __float_as_int(v), 0xB1, 0xF, 0xF, false));
    } else if constexpr (M == 2) { // quad_perm [2,3,0,1]
        return __int_as_float(__builtin_amdgcn_update_dpp(
            __float_as_int(v), __float_as_int(v), 0x4E, 0xF, 0xF, false));
    } else if constexpr (M == 4) { // ds_swizzle xor-4, imm pattern
        return __int_as_float(__builtin_amdgcn_ds_swizzle(
            __float_as_int(v), 0x101F));
    } else if constexpr (M == 8) { // row_ror:8 == xor-8 within 16-lane rows
        return __int_as_float(__builtin_amdgcn_update_dpp(
            __float_as_int(v), __float_as_int(v), 0x128, 0xF, 0xF, false));
    } else if constexpr (M == 16) {
        auto r = __builtin_amdgcn_permlane16_swap(
            (unsigned)__float_as_int(v), (unsigned)__float_as_int(v), false, false);
        return __int_as_float((int)(r[0] ^ r[1] ^ (unsigned)__float_as_int(v)));
    } else {                       // M == 32
        auto r = __builtin_amdgcn_permlane32_swap(
            (unsigned)__float_as_int(v), (unsigned)__float_as_int(v), false, false);
        return __int_as_float((int)(r[0] ^ r[1] ^ (unsigned)__float_as_int(v)));
    }
}

// RY butterfly on a lane-bit wire: a' = c*a + se*partner, se = own_bit ? +s : -s.
template<int M>
__device__ __forceinline__ void xwire(float c, float s, int lane,
                                      float (&sr)[16], float (&si)[16]) {
    const float se = (lane & M) ? s : -s;
    #pragma unroll
    for (int r = 0; r < 16; ++r) {
        float tr = xlane<M>(sr[r]);
        float ti = xlane<M>(si[r]);
        sr[r] = fmaf(c, sr[r], se * tr);
        si[r] = fmaf(c, si[r], se * ti);
    }
}

// Layout: one wave per batch element. Lane l holds amplitudes d = (l<<4)|r:
// register bits = qubits 0..3, lane bits = qubits 4..9.
__global__ __launch_bounds__(256)
void qnn_kernel(const float* __restrict__ x,
                const float* __restrict__ W_pre,
                const float* __restrict__ b_pre,
                const float* __restrict__ weights,
                const float* __restrict__ W_post,
                const float* __restrict__ b_post,
                float* __restrict__ out, int batch)
{
    const int lane = threadIdx.x & 63;
    const int b = blockIdx.x * 4 + (threadIdx.x >> 6);
    if (b >= batch) return;

    // 50 half-angle cos/sin pairs: lane j<50 owns weight j.
    float cw = 0.0f, sw = 0.0f;
    if (lane < (NL + 1) * NQ) {
        float th = 0.5f * weights[lane];
        __sincosf(th, &sw, &cw);
    }

    // h = x @ W_pre.T + b_pre : lane j<10 computes h_j.
    float hval = 0.0f;
    if (lane < NQ) {
        hval = b_pre[lane];
        #pragma unroll
        for (int k = 0; k < NQ; ++k)
            hval = fmaf(x[b * NQ + k], W_pre[lane * NQ + k], hval);
    }
    float h[NQ];
    #pragma unroll
    for (int i = 0; i < NQ; ++i) h[i] = bcastf(hval, i);
    float z[NQ - 1];
    #pragma unroll
    for (int i = 0; i < NQ - 1; ++i) z[i] = (PI_F - h[i]) * (PI_F - h[i + 1]);

    float A = 0.0f;
    #pragma unroll
    for (int i = 4; i < NQ; ++i)
        A += ((lane >> (i - 4)) & 1) ? -h[i] : h[i];
    #pragma unroll
    for (int i = 4; i < NQ - 1; ++i)
        A += (((lane >> (i - 4)) ^ (lane >> (i - 3))) & 1) ? -z[i] : z[i];

    const int plbase = (lane ^ (lane << 1)) & 0x3F;
    const int paddr0 = plbase << 2;
    const int paddr1 = (plbase ^ 1) << 2;

    #pragma clang loop unroll(disable)
    for (int rep = 0; rep < REPS; ++rep) {
        // State init: (1/32) * exp(-i*ang(d)).
        float sr[16], si[16];
        #pragma unroll
        for (int r = 0; r < 16; ++r) {
            float ang = A;
            #pragma unroll
            for (int i = 0; i < 4; ++i)
                ang += ((r >> i) & 1) ? -h[i] : h[i];
            #pragma unroll
            for (int i = 0; i < 3; ++i)
                ang += (((r >> i) ^ (r >> (i + 1))) & 1) ? -z[i] : z[i];
            ang += (((r >> 3) ^ lane) & 1) ? -z[3] : z[3];
            float sn, cn;
            __sincosf(ang, &sn, &cn);
            sr[r] = 0.03125f * cn;
            si[r] = -0.03125f * sn;
        }

        // Opacity barrier: values unchanged, but compiler cannot CSE the
        // downstream of rep 0 with rep 1.
        #pragma unroll
        for (int r = 0; r < 16; ++r) {
            asm volatile("" : "+v"(sr[r]), "+v"(si[r]));
        }

        #pragma clang loop unroll(disable)
        for (int l = 0; l <= NL; ++l) {
            if (l > 0) {
                // new[(l,r)] = old[(l', r')], r' = (r ^ (r<<1)) & 0xF
                float nr[16], ni[16];
                #pragma unroll
                for (int r = 0; r < 16; ++r) {
                    const int rp = (r ^ (r << 1)) & 0xF;
                    const int pa = (r < 8) ? paddr0 : paddr1;
                    nr[r] = __int_as_float(__builtin_amdgcn_ds_bpermute(pa, __float_as_int(sr[rp])));
                    ni[r] = __int_as_float(__builtin_amdgcn_ds_bpermute(pa, __float_as_int(si[rp])));
                }
                #pragma unroll
                for (int r = 0; r < 16; ++r) { sr[r] = nr[r]; si[r] = ni[r]; }
            }

            const int base = l * NQ;

            // RY wires 0..3: in-register butterflies.
            #pragma unroll
            for (int w = 0; w < 4; ++w) {
                const float c = bcastf(cw, base + w);
                const float s = bcastf(sw, base + w);
                #pragma unroll
                for (int r = 0; r < 16; ++r) {
                    if (r & (1 << w)) continue;
                    const int q = r | (1 << w);
                    float a0 = sr[r], a1 = sr[q];
                    sr[r] = fmaf(c, a0, -(s * a1));
                    sr[q] = fmaf(s, a0, c * a1);
                    float b0 = si[r], b1 = si[q];
                    si[r] = fmaf(c, b0, -(s * b1));
                    si[q] = fmaf(s, b0, c * b1);
                }
            }

            // RY wires 4..9: lane-bit butterflies.
            xwire<1 >(bcastf(cw, base + 4), bcastf(sw, base + 4), lane, sr, si);
            xwire<2 >(bcastf(cw, base + 5), bcastf(sw, base + 5), lane, sr, si);
            xwire<4 >(bcastf(cw, base + 6), bcastf(sw, base + 6), lane, sr, si);
            xwire<8 >(bcastf(cw, base + 7), bcastf(sw, base + 7), lane, sr, si);
            xwire<16>(bcastf(cw, base + 8), bcastf(sw, base + 8), lane, sr, si);
            xwire<32>(bcastf(cw, base + 9), bcastf(sw, base + 9), lane, sr, si);
        }

        // q_k = sum_d p(d) * (1 - 2*bit_k(d)).
        float P = 0.0f;
        float pk[NCL];
        #pragma unroll
        for (int k = 0; k < 4; ++k) pk[k] = 0.0f;
        #pragma unroll
        for (int r = 0; r < 16; ++r) {
            float pr = fmaf(sr[r], sr[r], si[r] * si[r]);
            P += pr;
            #pragma unroll
            for (int k = 0; k < 4; ++k)
                pk[k] += ((r >> k) & 1) ? -pr : pr;
        }
        #pragma unroll
        for (int k = 4; k < NCL; ++k)
            pk[k] = ((lane >> (k - 4)) & 1) ? -P : P;
        #pragma unroll
        for (int k = 0; k < NCL; ++k) {
            float v = pk[k];
            v += xlane<1>(v);
            v += xlane<2>(v);
            v += xlane<4>(v);
            v += xlane<8>(v);
            v += xlane<16>(v);
            v += xlane<32>(v);
            pk[k] = v;
        }

        if (lane < NCL) {
            float o = b_post[lane];
            #pragma unroll
            for (int k = 0; k < NCL; ++k)
                o = fmaf(pk[k], W_post[lane * NQ + k], o);
            out[b * NCL + lane] = o;
        }
    }
}

extern "C" void kernel_launch(void* const* d_in, const int* in_sizes, int n_in,
                              void* d_out, int out_size, void* d_ws, size_t ws_size,
                              hipStream_t stream) {
    const float* x       = (const float*)d_in[0];
    const float* W_pre   = (const float*)d_in[1];
    const float* b_pre   = (const float*)d_in[2];
    const float* weights = (const float*)d_in[3];
    const float* W_post  = (const float*)d_in[4];
    const float* b_post  = (const float*)d_in[5];
    float* outp = (float*)d_out;
    int batch = in_sizes[0] / NQ;
    int grid = (batch + 3) / 4;
    qnn_kernel<<<grid, 256, 0, stream>>>(x, W_pre, b_pre, weights, W_post, b_post, outp, batch);
}

// Round 8
// 33.215 us; speedup vs baseline: 1.4760x; 1.4760x over previous
//
#include <hip/hip_runtime.h>

#define NQ   10
#define NL   4
#define NCL  10
#define PI_F 3.14159265358979f

typedef float f2 __attribute__((ext_vector_type(2)));

// Broadcast lane l's value (l runtime-uniform) via v_readlane.
__device__ __forceinline__ float bcastf(float v, int l) {
    return __int_as_float(__builtin_amdgcn_readlane(__float_as_int(v), l));
}

__device__ __forceinline__ float bperm(int byteaddr, float v) {
    return __int_as_float(__builtin_amdgcn_ds_bpermute(byteaddr, __float_as_int(v)));
}

// Packed (re,im) fma — v_pk_fma_f32 when available.
__device__ __forceinline__ f2 fma2(f2 a, f2 b, f2 c) {
#if __has_builtin(__builtin_elementwise_fma)
    return __builtin_elementwise_fma(a, b, c);
#else
    f2 r; r.x = fmaf(a.x, b.x, c.x); r.y = fmaf(a.y, b.y, c.y); return r;
#endif
}

// Cross-lane xor-butterfly fetch: DPP / ds_swizzle / permlane_swap.
template<int M>
__device__ __forceinline__ float xlane(float v) {
    if constexpr (M == 1) {        // quad_perm [1,0,3,2]
        return __int_as_float(__builtin_amdgcn_update_dpp(
            __float_as_int(v), __float_as_int(v), 0xB1, 0xF, 0xF, false));
    } else if constexpr (M == 2) { // quad_perm [2,3,0,1]
        return __int_as_float(__builtin_amdgcn_update_dpp(
            __float_as_int(v), __float_as_int(v), 0x4E, 0xF, 0xF, false));
    } else if constexpr (M == 4) { // ds_swizzle xor-4 imm pattern
        return __int_as_float(__builtin_amdgcn_ds_swizzle(
            __float_as_int(v), 0x101F));
    } else if constexpr (M == 8) { // row_ror:8 == xor-8 within 16-lane rows
        return __int_as_float(__builtin_amdgcn_update_dpp(
            __float_as_int(v), __float_as_int(v), 0x128, 0xF, 0xF, false));
    } else if constexpr (M == 16) {
        auto r = __builtin_amdgcn_permlane16_swap(
            (unsigned)__float_as_int(v), (unsigned)__float_as_int(v), false, false);
        return __int_as_float((int)(r[0] ^ r[1] ^ (unsigned)__float_as_int(v)));
    } else {                       // M == 32
        auto r = __builtin_amdgcn_permlane32_swap(
            (unsigned)__float_as_int(v), (unsigned)__float_as_int(v), false, false);
        return __int_as_float((int)(r[0] ^ r[1] ^ (unsigned)__float_as_int(v)));
    }
}

template<int M>
__device__ __forceinline__ f2 xlane2(f2 v) {
    f2 r; r.x = xlane<M>(v.x); r.y = xlane<M>(v.y); return r;
}

// RY on a lane-bit wire: a' = c*a + se*partner, se = own_bit ? +s : -s.
template<int M>
__device__ __forceinline__ void xwire2(float c, float s, int lane, f2 (&sc)[8]) {
    const float se = (lane & M) ? s : -s;
    const f2 c2 = {c, c}, se2 = {se, se};
    #pragma unroll
    for (int r = 0; r < 8; ++r) {
        f2 t = xlane2<M>(sc[r]);
        sc[r] = fma2(se2, t, c2 * sc[r]);
    }
}

// Layout: TWO waves per batch element (4 waves/block = 2 elements/block).
// Lane holds 8 amplitudes d = (W<<9) | (lane<<3) | r:
//   qubits 0..2 = register bits r, qubits 3..8 = lane bits, qubit 9 = wave bit W.
__global__ __launch_bounds__(256)
void qnn_kernel(const float* __restrict__ x,
                const float* __restrict__ W_pre,
                const float* __restrict__ b_pre,
                const float* __restrict__ weights,
                const float* __restrict__ W_post,
                const float* __restrict__ b_post,
                float* __restrict__ out, int batch)
{
    __shared__ f2 xch[2][2][2][64][8];   // [pingpong][elem][W][lane][r]  = 32 KB
    __shared__ float sq[2][2][NCL];      // per-wave q_k partials

    const int tid  = threadIdx.x;
    const int lane = tid & 63;
    const int wv   = tid >> 6;   // 0..3
    const int eb   = wv >> 1;    // element within block
    const int W    = wv & 1;     // qubit-9 bit of this wave
    int b = blockIdx.x * 2 + eb;
    if (b >= batch) b = batch - 1;   // clamp (duplicate work, benign)

    // 50 half-angle cos/sin pairs: lane j<50 owns weight j (per wave).
    float cw = 0.0f, sw = 0.0f;
    if (lane < (NL + 1) * NQ) {
        float th = 0.5f * weights[lane];
        __sincosf(th, &sw, &cw);
    }

    // h = x @ W_pre.T + b_pre : lanes 0..9 compute h_j.
    float hval = 0.0f;
    if (lane < NQ) {
        hval = b_pre[lane];
        #pragma unroll
        for (int k = 0; k < NQ; ++k)
            hval = fmaf(x[b * NQ + k], W_pre[lane * NQ + k], hval);
    }
    float h[NQ];
    #pragma unroll
    for (int i = 0; i < NQ; ++i) h[i] = bcastf(hval, i);
    float z[NQ - 1];
    #pragma unroll
    for (int i = 0; i < NQ - 1; ++i) z[i] = (PI_F - h[i]) * (PI_F - h[i + 1]);

    // Lane/wave-constant angle part: qubits 3..9, zz pairs (3,4)..(8,9).
    float A = 0.0f;
    #pragma unroll
    for (int i = 0; i < 6; ++i)
        A += ((lane >> i) & 1) ? -h[3 + i] : h[3 + i];
    A += W ? -h[9] : h[9];
    #pragma unroll
    for (int j = 0; j < 5; ++j)
        A += (((lane >> j) ^ (lane >> (j + 1))) & 1) ? -z[3 + j] : z[3 + j];
    A += ((((lane >> 5) & 1) ^ W) & 1) ? -z[8] : z[8];

    // State init: (1/32) e^{-i ang}.
    f2 sc[8];
    #pragma unroll
    for (int r = 0; r < 8; ++r) {
        float ang = A;
        #pragma unroll
        for (int i = 0; i < 3; ++i)
            ang += ((r >> i) & 1) ? -h[i] : h[i];
        ang += ((r ^ (r >> 1)) & 1) ? -z[0] : z[0];          // pair (0,1)
        ang += (((r >> 1) ^ (r >> 2)) & 1) ? -z[1] : z[1];   // pair (1,2)
        ang += (((r >> 2) ^ lane) & 1) ? -z[2] : z[2];       // pair (2,3)
        float sn, cn;
        __sincosf(ang, &sn, &cn);
        sc[r].x = 0.03125f * cn;
        sc[r].y = -0.03125f * sn;
    }

    // CNOT-chain perm Q(d)=d^((d&0x1FF)<<1): lane part within wave.
    const int plbase = (lane ^ (lane << 1)) & 0x3F;
    int pp = 0;   // ping-pong buffer index

    #pragma clang loop unroll(disable)
    for (int l = 0; l <= NL; ++l) {
        if (l > 0) {
            // new[(W,L,r)] = old[(W^L5, L'', r'')]
            // Step 1 (own wave): tmp[r] = old[(W, L''(L,r), r''(r))]
            f2 tp[8];
            #pragma unroll
            for (int r = 0; r < 8; ++r) {
                const int srr = (r ^ (r << 1)) & 7;
                const int pa  = (plbase ^ ((r >> 2) & 1)) << 2;
                tp[r].x = bperm(pa, sc[srr].x);
                tp[r].y = bperm(pa, sc[srr].y);
            }
            // Step 2: lanes with L5=1 take the other wave's tmp.
            if (lane >= 32) {
                #pragma unroll
                for (int r = 0; r < 8; ++r) xch[pp][eb][W][lane][r] = tp[r];
            }
            __syncthreads();
            if (lane >= 32) {
                #pragma unroll
                for (int r = 0; r < 8; ++r) tp[r] = xch[pp][eb][W ^ 1][lane][r];
            }
            pp ^= 1;
            #pragma unroll
            for (int r = 0; r < 8; ++r) sc[r] = tp[r];
        }

        const int base = l * NQ;

        // Wires 0..2: in-register butterflies (packed re/im).
        #pragma unroll
        for (int w = 0; w < 3; ++w) {
            const float c = bcastf(cw, base + w);
            const float s = bcastf(sw, base + w);
            const f2 c2 = {c, c}, s2 = {s, s};
            #pragma unroll
            for (int r = 0; r < 8; ++r) {
                if (r & (1 << w)) continue;
                const int q = r | (1 << w);
                f2 a0 = sc[r], a1 = sc[q];
                f2 t = s2 * a1;
                sc[r] = fma2(c2, a0, -t);
                sc[q] = fma2(s2, a0, c2 * a1);
            }
        }

        // Wires 3..8: lane-bit butterflies.
        xwire2<1 >(bcastf(cw, base + 3), bcastf(sw, base + 3), lane, sc);
        xwire2<2 >(bcastf(cw, base + 4), bcastf(sw, base + 4), lane, sc);
        xwire2<4 >(bcastf(cw, base + 5), bcastf(sw, base + 5), lane, sc);
        xwire2<8 >(bcastf(cw, base + 6), bcastf(sw, base + 6), lane, sc);
        xwire2<16>(bcastf(cw, base + 7), bcastf(sw, base + 7), lane, sc);
        xwire2<32>(bcastf(cw, base + 8), bcastf(sw, base + 8), lane, sc);

        // Wire 9: cross-wave butterfly via LDS exchange.
        {
            const float c = bcastf(cw, base + 9);
            const float s = bcastf(sw, base + 9);
            #pragma unroll
            for (int r = 0; r < 8; ++r) xch[pp][eb][W][lane][r] = sc[r];
            __syncthreads();
            const float se = W ? s : -s;
            const f2 c2 = {c, c}, se2 = {se, se};
            #pragma unroll
            for (int r = 0; r < 8; ++r) {
                f2 t = xch[pp][eb][W ^ 1][lane][r];
                sc[r] = fma2(se2, t, c2 * sc[r]);
            }
            pp ^= 1;
        }
    }

    // Probabilities and q_k = sum_d p(d)*(1-2 bit_k(d)).
    float P = 0.0f, p0 = 0.0f, p1 = 0.0f, p2 = 0.0f;
    #pragma unroll
    for (int r = 0; r < 8; ++r) {
        f2 qq = sc[r] * sc[r];
        float pr = qq.x + qq.y;
        P  += pr;
        p0 += (r & 1) ? -pr : pr;
        p1 += (r & 2) ? -pr : pr;
        p2 += (r & 4) ? -pr : pr;
    }
    // Plain butterfly sums (all lanes end with the wave total).
    #pragma unroll
    for (int st = 0; st < 6; ++st) {
        const int m = 1 << st;
        if (m == 1)  { p0 += xlane<1 >(p0); p1 += xlane<1 >(p1); p2 += xlane<1 >(p2); }
        if (m == 2)  { p0 += xlane<2 >(p0); p1 += xlane<2 >(p1); p2 += xlane<2 >(p2); }
        if (m == 4)  { p0 += xlane<4 >(p0); p1 += xlane<4 >(p1); p2 += xlane<4 >(p2); }
        if (m == 8)  { p0 += xlane<8 >(p0); p1 += xlane<8 >(p1); p2 += xlane<8 >(p2); }
        if (m == 16) { p0 += xlane<16>(p0); p1 += xlane<16>(p1); p2 += xlane<16>(p2); }
        if (m == 32) { p0 += xlane<32>(p0); p1 += xlane<32>(p1); p2 += xlane<32>(p2); }
    }
    // Walsh transform of P over lanes: lane m ends with sum_l (-1)^{popc(l&m)} P_l.
    {
        float t;
        t = xlane<1 >(P); P = t + ((lane & 1 ) ? -P : P);
        t = xlane<2 >(P); P = t + ((lane & 2 ) ? -P : P);
        t = xlane<4 >(P); P = t + ((lane & 4 ) ? -P : P);
        t = xlane<8 >(P); P = t + ((lane & 8 ) ? -P : P);
        t = xlane<16>(P); P = t + ((lane & 16) ? -P : P);
        t = xlane<32>(P); P = t + ((lane & 32) ? -P : P);
    }
    // Scatter per-wave partials: lane0 holds T, lane (1<<j) holds S_j (qubit 3+j).
    if (lane == 0)  sq[eb][W][9] = W ? -P : P;
    if (lane == 1)  sq[eb][W][3] = P;
    if (lane == 2)  sq[eb][W][4] = P;
    if (lane == 4)  sq[eb][W][5] = P;
    if (lane == 8)  sq[eb][W][6] = P;
    if (lane == 16) sq[eb][W][7] = P;
    if (lane == 32) sq[eb][W][8] = P;
    if (lane == 33) sq[eb][W][0] = p0;
    if (lane == 34) sq[eb][W][1] = p1;
    if (lane == 35) sq[eb][W][2] = p2;
    __syncthreads();

    if (W == 0 && lane < NCL) {
        float o = b_post[lane];
        #pragma unroll
        for (int k = 0; k < NCL; ++k)
            o = fmaf(sq[eb][0][k] + sq[eb][1][k], W_post[lane * NQ + k], o);
        out[b * NCL + lane] = o;
    }
}

extern "C" void kernel_launch(void* const* d_in, const int* in_sizes, int n_in,
                              void* d_out, int out_size, void* d_ws, size_t ws_size,
                              hipStream_t stream) {
    const float* x       = (const float*)d_in[0];
    const float* W_pre   = (const float*)d_in[1];
    const float* b_pre   = (const float*)d_in[2];
    const float* weights = (const float*)d_in[3];
    const float* W_post  = (const float*)d_in[4];
    const float* b_post  = (const float*)d_in[5];
    float* outp = (float*)d_out;
    int batch = in_sizes[0] / NQ;
    int grid = (batch + 1) / 2;
    qnn_kernel<<<grid, 256, 0, stream>>>(x, W_pre, b_pre, weights, W_post, b_post, outp, batch);
}

// Round 11
// 27.989 us; speedup vs baseline: 1.7516x; 1.1867x over previous
//
#include <hip/hip_runtime.h>

#define NQ   10
#define NL   4
#define NCL  10
#define PI_F 3.14159265358979f

typedef float f2 __attribute__((ext_vector_type(2)));

// Broadcast lane l's value (uniform l) via v_readlane.
__device__ __forceinline__ float bcastf(float v, int l) {
    return __int_as_float(__builtin_amdgcn_readlane(__float_as_int(v), l));
}

__device__ __forceinline__ float bperm(int byteaddr, float v) {
    return __int_as_float(__builtin_amdgcn_ds_bpermute(byteaddr, __float_as_int(v)));
}

// Packed fma: v_pk_fma_f32.
__device__ __forceinline__ f2 fma2(f2 a, f2 b, f2 c) {
#if __has_builtin(__builtin_elementwise_fma)
    return __builtin_elementwise_fma(a, b, c);
#else
    f2 r; r.x = fmaf(a.x, b.x, c.x); r.y = fmaf(a.y, b.y, c.y); return r;
#endif
}

// Cross-lane xor-butterfly fetch: DPP / ds_swizzle / permlane_swap (all validated R5-R7).
template<int M>
__device__ __forceinline__ float xlane(float v) {
    if constexpr (M == 1) {        // quad_perm [1,0,3,2]
        return __int_as_float(__builtin_amdgcn_update_dpp(
            __float_as_int(v), __float_as_int(v), 0xB1, 0xF, 0xF, false));
    } else if constexpr (M == 2) { // quad_perm [2,3,0,1]
        return __int_as_float(__builtin_amdgcn_update_dpp(
            __float_as_int(v), __float_as_int(v), 0x4E, 0xF, 0xF, false));
    } else if constexpr (M == 4) { // ds_swizzle xor-4 imm pattern
        return __int_as_float(__builtin_amdgcn_ds_swizzle(
            __float_as_int(v), 0x101F));
    } else if constexpr (M == 8) { // row_ror:8 == xor-8 within 16-lane rows
        return __int_as_float(__builtin_amdgcn_update_dpp(
            __float_as_int(v), __float_as_int(v), 0x128, 0xF, 0xF, false));
    } else if constexpr (M == 16) {
        auto r = __builtin_amdgcn_permlane16_swap(
            (unsigned)__float_as_int(v), (unsigned)__float_as_int(v), false, false);
        return __int_as_float((int)(r[0] ^ r[1] ^ (unsigned)__float_as_int(v)));
    } else {                       // M == 32
        auto r = __builtin_amdgcn_permlane32_swap(
            (unsigned)__float_as_int(v), (unsigned)__float_as_int(v), false, false);
        return __int_as_float((int)(r[0] ^ r[1] ^ (unsigned)__float_as_int(v)));
    }
}

template<int M>
__device__ __forceinline__ f2 xlane2(f2 v) {
    f2 r; r.x = xlane<M>(v.x); r.y = xlane<M>(v.y); return r;
}

// RY on a lane-bit wire (packed): sc' = c*sc + se*partner.
template<int M>
__device__ __forceinline__ void xwire2(float c, float s, int lane, f2 (&sc)[16]) {
    const float se = (lane & M) ? s : -s;
    const f2 c2 = {c, c}, se2 = {se, se};
    #pragma unroll
    for (int r = 0; r < 16; ++r) {
        f2 t = xlane2<M>(sc[r]);
        sc[r] = fma2(se2, t, c2 * sc[r]);
    }
}

// Full-wave butterfly sum, packed pair.
__device__ __forceinline__ f2 bsum2(f2 v) {
    v += xlane2<1 >(v); v += xlane2<2 >(v); v += xlane2<4 >(v);
    v += xlane2<8 >(v); v += xlane2<16>(v); v += xlane2<32>(v);
    return v;
}

// Layout: one wave per batch element. Lane l holds amplitudes d = (l<<4)|r
// as f2{re,im}: register bits = qubits 0..3, lane bits = qubits 4..9.
__global__ __launch_bounds__(256)
void qnn_kernel(const float* __restrict__ x,
                const float* __restrict__ W_pre,
                const float* __restrict__ b_pre,
                const float* __restrict__ weights,
                const float* __restrict__ W_post,
                const float* __restrict__ b_post,
                float* __restrict__ out, int batch)
{
    const int lane = threadIdx.x & 63;
    const int b = blockIdx.x * 4 + (threadIdx.x >> 6);
    if (b >= batch) return;
    const int bu = __builtin_amdgcn_readfirstlane(b);   // wave-uniform

    // 50 half-angle cos/sin pairs: lane j<50 owns weight j (readlane per wire).
    float cw = 0.0f, sw = 0.0f;
    if (lane < (NL + 1) * NQ) {
        float th = 0.5f * weights[lane];
        __sincosf(th, &sw, &cw);
    }

    // h = x @ W_pre.T + b_pre : ALL lanes compute all 10 (uniform, scalarizable).
    float xv[NQ];
    #pragma unroll
    for (int k = 0; k < NQ; ++k) xv[k] = x[bu * NQ + k];
    float h[NQ];
    #pragma unroll
    for (int j = 0; j < NQ; ++j) {
        float acc = b_pre[j];
        #pragma unroll
        for (int k = 0; k < NQ; ++k)
            acc = fmaf(xv[k], W_pre[j * NQ + k], acc);
        h[j] = acc;
    }
    float z[NQ - 1];
    #pragma unroll
    for (int i = 0; i < NQ - 1; ++i) z[i] = (PI_F - h[i]) * (PI_F - h[i + 1]);

    // Lane-constant angle part (qubits 4..9, zz pairs (4,5)..(8,9)).
    float A = 0.0f;
    #pragma unroll
    for (int i = 4; i < NQ; ++i)
        A += ((lane >> (i - 4)) & 1) ? -h[i] : h[i];
    #pragma unroll
    for (int i = 4; i < NQ - 1; ++i)
        A += (((lane >> (i - 4)) ^ (lane >> (i - 3))) & 1) ? -z[i] : z[i];

    // State init: (1/32) e^{-i ang}.
    f2 sc[16];
    #pragma unroll
    for (int r = 0; r < 16; ++r) {
        float ang = A;
        #pragma unroll
        for (int i = 0; i < 4; ++i)
            ang += ((r >> i) & 1) ? -h[i] : h[i];
        #pragma unroll
        for (int i = 0; i < 3; ++i)
            ang += (((r >> i) ^ (r >> (i + 1))) & 1) ? -z[i] : z[i];
        ang += (((r >> 3) ^ lane) & 1) ? -z[3] : z[3];
        float sn, cn;
        __sincosf(ang, &sn, &cn);
        sc[r].x = 0.03125f * cn;
        sc[r].y = -0.03125f * sn;
    }

    // CNOT-chain perm lane part: l' = ((l ^ (l<<1)) & 0x3F) ^ r3.
    const int plbase = (lane ^ (lane << 1)) & 0x3F;
    const int paddr0 = plbase << 2;
    const int paddr1 = (plbase ^ 1) << 2;

    #pragma clang loop unroll(disable)
    for (int l = 0; l <= NL; ++l) {
        if (l > 0) {
            // new[(l,r)] = old[(l', r')], r' = (r ^ (r<<1)) & 0xF
            f2 np[16];
            #pragma unroll
            for (int r = 0; r < 16; ++r) {
                const int rp = (r ^ (r << 1)) & 0xF;
                const int pa = (r < 8) ? paddr0 : paddr1;
                np[r].x = bperm(pa, sc[rp].x);
                np[r].y = bperm(pa, sc[rp].y);
            }
            #pragma unroll
            for (int r = 0; r < 16; ++r) sc[r] = np[r];
        }

        const int base = l * NQ;

        // Wires 0..3: in-register butterflies, packed.
        #pragma unroll
        for (int w = 0; w < 4; ++w) {
            const float c = bcastf(cw, base + w);
            const float s = bcastf(sw, base + w);
            const f2 c2 = {c, c}, s2 = {s, s};
            #pragma unroll
            for (int r = 0; r < 16; ++r) {
                if (r & (1 << w)) continue;
                const int q = r | (1 << w);
                f2 a0 = sc[r], a1 = sc[q];
                sc[r] = fma2(c2, a0, -(s2 * a1));
                sc[q] = fma2(s2, a0, c2 * a1);
            }
        }

        // Wires 4..9: lane-bit butterflies, packed.
        xwire2<1 >(bcastf(cw, base + 4), bcastf(sw, base + 4), lane, sc);
        xwire2<2 >(bcastf(cw, base + 5), bcastf(sw, base + 5), lane, sc);
        xwire2<4 >(bcastf(cw, base + 6), bcastf(sw, base + 6), lane, sc);
        xwire2<8 >(bcastf(cw, base + 7), bcastf(sw, base + 7), lane, sc);
        xwire2<16>(bcastf(cw, base + 8), bcastf(sw, base + 8), lane, sc);
        xwire2<32>(bcastf(cw, base + 9), bcastf(sw, base + 9), lane, sc);
    }

    // Probabilities and q_k.
    float P = 0.0f, p0 = 0.0f, p1 = 0.0f, p2 = 0.0f, p3 = 0.0f;
    #pragma unroll
    for (int r = 0; r < 16; ++r) {
        f2 qq = sc[r] * sc[r];
        float pr = qq.x + qq.y;
        P  += pr;
        p0 += (r & 1) ? -pr : pr;
        p1 += (r & 2) ? -pr : pr;
        p2 += (r & 4) ? -pr : pr;
        p3 += (r & 8) ? -pr : pr;
    }
    // q_0..3: packed butterfly sums (all lanes get totals).
    f2 qa = bsum2((f2){p0, p1});
    f2 qb = bsum2((f2){p2, p3});
    // q_4..9: Walsh transform of P over lanes; value at lane 2^j.
    {
        float t;
        t = xlane<1 >(P); P = t + ((lane & 1 ) ? -P : P);
        t = xlane<2 >(P); P = t + ((lane & 2 ) ? -P : P);
        t = xlane<4 >(P); P = t + ((lane & 4 ) ? -P : P);
        t = xlane<8 >(P); P = t + ((lane & 8 ) ? -P : P);
        t = xlane<16>(P); P = t + ((lane & 16) ? -P : P);
        t = xlane<32>(P); P = t + ((lane & 32) ? -P : P);
    }
    float q[NCL];
    q[0] = qa.x; q[1] = qa.y; q[2] = qb.x; q[3] = qb.y;
    q[4] = bcastf(P, 1);
    q[5] = bcastf(P, 2);
    q[6] = bcastf(P, 4);
    q[7] = bcastf(P, 8);
    q[8] = bcastf(P, 16);
    q[9] = bcastf(P, 32);

    if (lane < NCL) {
        float o = b_post[lane];
        #pragma unroll
        for (int k = 0; k < NCL; ++k)
            o = fmaf(q[k], W_post[lane * NQ + k], o);
        out[b * NCL + lane] = o;
    }
}

extern "C" void kernel_launch(void* const* d_in, const int* in_sizes, int n_in,
                              void* d_out, int out_size, void* d_ws, size_t ws_size,
                              hipStream_t stream) {
    const float* x       = (const float*)d_in[0];
    const float* W_pre   = (const float*)d_in[1];
    const float* b_pre   = (const float*)d_in[2];
    const float* weights = (const float*)d_in[3];
    const float* W_post  = (const float*)d_in[4];
    const float* b_post  = (const float*)d_in[5];
    float* outp = (float*)d_out;
    int batch = in_sizes[0] / NQ;
    int grid = (batch + 3) / 4;
    qnn_kernel<<<grid, 256, 0, stream>>>(x, W_pre, b_pre, weights, W_post, b_post, outp, batch);
}